// Round 1
// baseline (331.669 us; speedup 1.0000x reference)
//
#include <hip/hip_runtime.h>
#include <cstdint>
#include <cstddef>

typedef unsigned short u16;
typedef __attribute__((ext_vector_type(8))) short bf16x8;
typedef __attribute__((ext_vector_type(4))) float f32x4;

#define DEV static __device__ __forceinline__

DEV void gload_lds16(const void* g, void* l) {
  __builtin_amdgcn_global_load_lds((const __attribute__((address_space(1))) void*)g,
                                   (__attribute__((address_space(3))) void*)l, 16, 0, 0);
}

DEV u16 f2bf(float f) {  // RNE fp32 -> bf16 (finite inputs)
  unsigned x = __float_as_uint(f);
  return (u16)((x + 0x7FFFu + ((x >> 16) & 1u)) >> 16);
}

// ---------------- fp32 -> bf16 convert ----------------
__global__ __launch_bounds__(256) void cvt_bf16(const float* __restrict__ in,
                                                u16* __restrict__ out, int n) {
  int i = (blockIdx.x * 256 + threadIdx.x) * 4;
  if (i + 3 < n) {
    float4 v = *(const float4*)(in + i);
    uint2 p;
    p.x = (unsigned)f2bf(v.x) | ((unsigned)f2bf(v.y) << 16);
    p.y = (unsigned)f2bf(v.z) | ((unsigned)f2bf(v.w) << 16);
    *(uint2*)(out + i) = p;
  }
}

// ---------------- GEMM: C = A * B^T (+bias) ----------------
// A[M][K] bf16 row-major, Bm[N][K] bf16 row-major (B-transposed input).
// EPI 0: Cout = float[M][N], v + bias[e]
// EPI 1: QKV scatter: e -> (which,h,d), row -> (b,s); write bf16 to [which][b][h][s][d]
template <int EPI>
__global__ __launch_bounds__(256) void gemm_bt(const u16* __restrict__ A,
                                               const u16* __restrict__ Bm,
                                               const float* __restrict__ bias,
                                               void* __restrict__ Cout,
                                               int M, int N, int K) {
  __shared__ u16 As[2][128 * 32];
  __shared__ u16 Bs[2][128 * 32];
  const int nb = N >> 7;
  const int m0 = (int)(blockIdx.x / nb) << 7;
  const int n0 = (int)(blockIdx.x % nb) << 7;
  const int tid = threadIdx.x;
  const int w = tid >> 6, lane = tid & 63;
  const int wm = (w >> 1) << 6, wn = (w & 1) << 6;   // wave origin in 128x128 tile
  const int lr = lane & 15, lg = lane >> 4;

  f32x4 acc[4][4];
  const f32x4 z4 = {0.f, 0.f, 0.f, 0.f};
#pragma unroll
  for (int m = 0; m < 4; ++m)
#pragma unroll
    for (int n = 0; n < 4; ++n) acc[m][n] = z4;

  auto stage = [&](int ks, int buf) {
    const int k0 = ks << 5;
#pragma unroll
    for (int iss = 0; iss < 2; ++iss) {
      const int o = iss * 256 + tid;        // 16B chunk id 0..511
      const int row = o >> 2, c = o & 3;    // 4 chunks per 32-elem row
      gload_lds16(A + (size_t)(m0 + row) * K + k0 + c * 8,
                  &As[buf][(iss * 256 + w * 64) * 8]);
      gload_lds16(Bm + (size_t)(n0 + row) * K + k0 + c * 8,
                  &Bs[buf][(iss * 256 + w * 64) * 8]);
    }
  };

  const int nk = K >> 5;
  stage(0, 0);
  __syncthreads();
  for (int ks = 0; ks < nk; ++ks) {
    const int cur = ks & 1;
    if (ks + 1 < nk) stage(ks + 1, cur ^ 1);
    bf16x8 af[4], bfr[4];
#pragma unroll
    for (int m = 0; m < 4; ++m)
      af[m] = *(const bf16x8*)&As[cur][(wm + m * 16 + lr) * 32 + lg * 8];
#pragma unroll
    for (int n = 0; n < 4; ++n)
      bfr[n] = *(const bf16x8*)&Bs[cur][(wn + n * 16 + lr) * 32 + lg * 8];
#pragma unroll
    for (int m = 0; m < 4; ++m)
#pragma unroll
      for (int n = 0; n < 4; ++n)
        acc[m][n] = __builtin_amdgcn_mfma_f32_16x16x32_bf16(af[m], bfr[n], acc[m][n], 0, 0, 0);
    __syncthreads();
  }

#pragma unroll
  for (int n = 0; n < 4; ++n) {
    const int e = n0 + wn + n * 16 + lr;
    const float bv = bias[e];
#pragma unroll
    for (int m = 0; m < 4; ++m) {
#pragma unroll
      for (int r = 0; r < 4; ++r) {
        const int row = m0 + wm + m * 16 + lg * 4 + r;   // D: col=lane&15, row=(lane>>4)*4+r
        const float v = acc[m][n][r] + bv;
        if (EPI == 0) {
          ((float*)Cout)[(size_t)row * N + e] = v;
        } else {
          const int which = e >> 10, h = (e >> 6) & 15, d = e & 63;
          const int b = row >> 11, s = row & 2047;
          ((u16*)Cout)[(size_t)which * 4194304 + (((size_t)(b * 16 + h) * 2048 + s) << 6) + d] =
              f2bf(v);
        }
      }
    }
  }
}

// ---------------- V transpose: [bh][t][d] -> [bh][d][t] ----------------
__global__ __launch_bounds__(256) void vtrans(const u16* __restrict__ V, u16* __restrict__ Vt) {
  __shared__ u16 tile[64][72];
  const int bh = blockIdx.x >> 5, t0 = (int)(blockIdx.x & 31) << 6;
  const int tid = threadIdx.x;
  {
    const int tr = tid >> 2, dc = (tid & 3) << 4;
    const u16* src = V + ((size_t)bh * 2048 + t0 + tr) * 64 + dc;
    *(int4*)&tile[tr][dc] = *(const int4*)src;
    *(int4*)&tile[tr][dc + 8] = *(const int4*)(src + 8);
  }
  __syncthreads();
  {
    const int dr = tid >> 2, ts = (tid & 3) << 4;
    unsigned pk[8];
#pragma unroll
    for (int j = 0; j < 8; ++j)
      pk[j] = (unsigned)tile[ts + 2 * j][dr] | ((unsigned)tile[ts + 2 * j + 1][dr] << 16);
    u16* dst = Vt + ((size_t)bh * 64 + dr) * 2048 + t0 + ts;
    *(int4*)dst = *(int4*)&pk[0];
    *(int4*)(dst + 8) = *(int4*)&pk[4];
  }
}

// ---------------- fused attention ----------------
// grid: bh(32) x qtile(32).  4 waves, each owns 16 q-rows.
// pass 1: online (m,l) per row.  pass 2: recompute scores, write weights fp32,
// accumulate P*V (P through per-wave swizzled LDS, V from transposed Vt tiles).
__global__ __launch_bounds__(256) void attn(const u16* __restrict__ Q,
                                            const u16* __restrict__ Kg,
                                            const u16* __restrict__ Vtg,
                                            const int* __restrict__ mask,
                                            float* __restrict__ Wout,
                                            u16* __restrict__ Og) {
  __shared__ u16 Ks[2][64 * 64];
  __shared__ u16 Vs[2][64 * 64];
  __shared__ u16 Pl[4][16 * 64];
  const int bh = blockIdx.x >> 5, qt = blockIdx.x & 31;
  const int b = bh >> 4, h = bh & 15;
  const int tid = threadIdx.x;
  const int w = tid >> 6, lane = tid & 63;
  const int lr = lane & 15, lg = lane >> 4;
  const int srow0 = qt * 64 + w * 16;

  const u16* qrow = Q + ((size_t)bh * 2048 + srow0 + lr) * 64;
  const bf16x8 qf0 = *(const bf16x8*)(qrow + lg * 8);
  const bf16x8 qf1 = *(const bf16x8*)(qrow + 32 + lg * 8);
  const int* mrow = mask + b * 2048;

  auto stageK = [&](int kt, int buf) {
    const u16* g = Kg + ((size_t)bh * 2048 + kt * 64) * 64;
#pragma unroll
    for (int iss = 0; iss < 2; ++iss) {
      const int o = iss * 256 + tid;
      const int row = o >> 3, c = o & 7;   // 8 chunks per 64-elem row, XOR-swizzled
      gload_lds16(g + row * 64 + ((c ^ (row & 7)) << 3), &Ks[buf][(iss * 256 + w * 64) * 8]);
    }
  };
  auto stageV = [&](int kt, int buf) {
    const u16* g = Vtg + (size_t)bh * 131072 + kt * 64;
#pragma unroll
    for (int iss = 0; iss < 2; ++iss) {
      const int o = iss * 256 + tid;
      const int row = o >> 3, c = o & 7;
      gload_lds16(g + (size_t)row * 2048 + ((c ^ (row & 7)) << 3),
                  &Vs[buf][(iss * 256 + w * 64) * 8]);
    }
  };
  auto scores = [&](int cur, int kt, f32x4* sc) {
    const f32x4 z4 = {0.f, 0.f, 0.f, 0.f};
#pragma unroll
    for (int n = 0; n < 4; ++n) {
      sc[n] = z4;
      const int tr = n * 16 + lr;
      const bf16x8 k0 = *(const bf16x8*)&Ks[cur][tr * 64 + ((lg ^ (tr & 7)) << 3)];
      const bf16x8 k1 = *(const bf16x8*)&Ks[cur][tr * 64 + (((lg + 4) ^ (tr & 7)) << 3)];
      sc[n] = __builtin_amdgcn_mfma_f32_16x16x32_bf16(qf0, k0, sc[n], 0, 0, 0);
      sc[n] = __builtin_amdgcn_mfma_f32_16x16x32_bf16(qf1, k1, sc[n], 0, 0, 0);
      if (mrow[kt * 64 + n * 16 + lr] == 0) {
        sc[n][0] = -4e30f; sc[n][1] = -4e30f; sc[n][2] = -4e30f; sc[n][3] = -4e30f;
      }
    }
  };

  float mreg[4] = {-1e30f, -1e30f, -1e30f, -1e30f};
  float lreg[4] = {0.f, 0.f, 0.f, 0.f};

  // ---- pass 1: row stats ----
  stageK(0, 0);
  __syncthreads();
  for (int kt = 0; kt < 32; ++kt) {
    const int cur = kt & 1;
    if (kt + 1 < 32) stageK(kt + 1, cur ^ 1);
    f32x4 sc[4];
    scores(cur, kt, sc);
#pragma unroll
    for (int r = 0; r < 4; ++r) {
      float tm = fmaxf(fmaxf(sc[0][r], sc[1][r]), fmaxf(sc[2][r], sc[3][r]));
      tm = fmaxf(tm, __shfl_xor(tm, 1));
      tm = fmaxf(tm, __shfl_xor(tm, 2));
      tm = fmaxf(tm, __shfl_xor(tm, 4));
      tm = fmaxf(tm, __shfl_xor(tm, 8));
      const float mn = fmaxf(mreg[r], tm);
      float sum = 0.f;
#pragma unroll
      for (int n = 0; n < 4; ++n) sum += __expf(0.125f * (sc[n][r] - mn));
      sum += __shfl_xor(sum, 1);
      sum += __shfl_xor(sum, 2);
      sum += __shfl_xor(sum, 4);
      sum += __shfl_xor(sum, 8);
      lreg[r] = lreg[r] * __expf(0.125f * (mreg[r] - mn)) + sum;
      mreg[r] = mn;
    }
    __syncthreads();
  }

  float rl[4];
#pragma unroll
  for (int r = 0; r < 4; ++r) rl[r] = 1.0f / lreg[r];

  // ---- pass 2: weights + PV ----
  stageK(0, 0);
  stageV(0, 0);
  __syncthreads();

  f32x4 oacc[4];
  const f32x4 z4 = {0.f, 0.f, 0.f, 0.f};
#pragma unroll
  for (int n = 0; n < 4; ++n) oacc[n] = z4;

  float* wrow = Wout + ((size_t)bh * 2048 + srow0) * 2048;
  u16* plw = &Pl[w][0];

  for (int kt = 0; kt < 32; ++kt) {
    const int cur = kt & 1;
    if (kt + 1 < 32) { stageK(kt + 1, cur ^ 1); stageV(kt + 1, cur ^ 1); }
    f32x4 sc[4];
    scores(cur, kt, sc);
#pragma unroll
    for (int n = 0; n < 4; ++n) {
      const int t = kt * 64 + n * 16 + lr;
      const int tl2 = (n * 16 + lr) * 2;
#pragma unroll
      for (int r = 0; r < 4; ++r) {
        const float wv = __expf(0.125f * (sc[n][r] - mreg[r])) * rl[r];
        wrow[(size_t)(lg * 4 + r) * 2048 + t] = wv;
        const int sl = lg * 4 + r;   // swizzled per-wave P store (bits 4-6 XOR)
        *(u16*)((char*)plw + (sl * 128 + (tl2 ^ ((sl & 7) << 4)))) = f2bf(wv);
      }
    }
    // read P as A-fragments (per-wave private LDS; in-wave ordering by compiler)
    const int pbase = lr * 128;
    const bf16x8 pf0 = *(const bf16x8*)((const char*)plw + (pbase + ((lg * 16) ^ ((lr & 7) << 4))));
    const bf16x8 pf1 = *(const bf16x8*)((const char*)plw + (pbase + ((64 + lg * 16) ^ ((lr & 7) << 4))));
#pragma unroll
    for (int n = 0; n < 4; ++n) {
      const int dr = n * 16 + lr;
      const bf16x8 v0 = *(const bf16x8*)&Vs[cur][dr * 64 + ((lg ^ (dr & 7)) << 3)];
      const bf16x8 v1 = *(const bf16x8*)&Vs[cur][dr * 64 + (((lg + 4) ^ (dr & 7)) << 3)];
      oacc[n] = __builtin_amdgcn_mfma_f32_16x16x32_bf16(pf0, v0, oacc[n], 0, 0, 0);
      oacc[n] = __builtin_amdgcn_mfma_f32_16x16x32_bf16(pf1, v1, oacc[n], 0, 0, 0);
    }
    __syncthreads();
  }

#pragma unroll
  for (int n = 0; n < 4; ++n) {
#pragma unroll
    for (int r = 0; r < 4; ++r) {
      const int s = srow0 + lg * 4 + r;
      Og[((size_t)(b * 2048 + s)) * 1024 + h * 64 + n * 16 + lr] = f2bf(oacc[n][r]);
    }
  }
}

// ---------------- launch ----------------
extern "C" void kernel_launch(void* const* d_in, const int* in_sizes, int n_in,
                              void* d_out, int out_size, void* d_ws, size_t ws_size,
                              hipStream_t stream) {
  const float* x     = (const float*)d_in[0];
  const int*   mask  = (const int*)d_in[1];
  const float* qkv_w = (const float*)d_in[2];
  const float* qkv_b = (const float*)d_in[3];
  const float* wo_w  = (const float*)d_in[4];
  const float* wo_b  = (const float*)d_in[5];
  float* out = (float*)d_out;

  char* ws = (char*)d_ws;
  u16* xb   = (u16*)(ws);                          // 4096x1024
  u16* qwb  = (u16*)(ws + (8u << 20));             // 3072x1024
  u16* wob  = (u16*)(ws + (14u << 20));            // 1024x1024
  u16* qkvb = (u16*)(ws + (16u << 20));            // 3 x [bh][s][64] bf16
  u16* vt   = (u16*)(ws + (40u << 20));            // [bh][64][2048] bf16
  u16* ob   = (u16*)(ws + (48u << 20));            // attn out [4096][1024] bf16

  cvt_bf16<<<4096, 256, 0, stream>>>(x, xb, 4194304);
  cvt_bf16<<<3072, 256, 0, stream>>>(qkv_w, qwb, 3145728);
  cvt_bf16<<<1024, 256, 0, stream>>>(wo_w, wob, 1048576);
  gemm_bt<1><<<768, 256, 0, stream>>>(xb, qwb, qkv_b, qkvb, 4096, 3072, 1024);
  vtrans<<<1024, 256, 0, stream>>>(qkvb + 2 * 4194304, vt);
  attn<<<1024, 256, 0, stream>>>(qkvb, qkvb + 4194304, vt, mask, out + 4194304, ob);
  gemm_bt<0><<<256, 256, 0, stream>>>(ob, wob, wo_b, out, 4096, 1024, 1024);
}

// Round 2
// 309.137 us; speedup vs baseline: 1.0729x; 1.0729x over previous
//
#include <hip/hip_runtime.h>
#include <cstdint>
#include <cstddef>

typedef unsigned short u16;
typedef __attribute__((ext_vector_type(8))) short bf16x8;
typedef __attribute__((ext_vector_type(4))) float f32x4;

#define DEV static __device__ __forceinline__

DEV void gload_lds16(const void* g, void* l) {
  __builtin_amdgcn_global_load_lds((const __attribute__((address_space(1))) void*)g,
                                   (__attribute__((address_space(3))) void*)l, 16, 0, 0);
}

DEV u16 f2bf(float f) {  // RNE fp32 -> bf16 (finite inputs)
  unsigned x = __float_as_uint(f);
  return (u16)((x + 0x7FFFu + ((x >> 16) & 1u)) >> 16);
}

DEV unsigned cvtpk(float lo, float hi) {  // bf16(lo) in [15:0], bf16(hi) in [31:16]
  unsigned r;
  asm("v_cvt_pk_bf16_f32 %0, %1, %2" : "=v"(r) : "v"(lo), "v"(hi));
  return r;
}

// ---------------- fp32 -> bf16 convert ----------------
__global__ __launch_bounds__(256) void cvt_bf16(const float* __restrict__ in,
                                                u16* __restrict__ out, int n) {
  int i = (blockIdx.x * 256 + threadIdx.x) * 4;
  if (i + 3 < n) {
    float4 v = *(const float4*)(in + i);
    uint2 p;
    p.x = (unsigned)f2bf(v.x) | ((unsigned)f2bf(v.y) << 16);
    p.y = (unsigned)f2bf(v.z) | ((unsigned)f2bf(v.w) << 16);
    *(uint2*)(out + i) = p;
  }
}

// ---------------- GEMM: C = A * B^T (+bias) ----------------
// A[M][K] bf16 row-major, Bm[N][K] bf16 row-major (B-transposed input).
// EPI 0: Cout = float[M][N], v + bias[e]
// EPI 1: QKV scatter: e -> (which,h,d), row -> (b,s); write bf16 to [which][b][h][s][d]
template <int EPI, int BM, int BN>
__global__ __launch_bounds__(256) void gemm_bt(const u16* __restrict__ A,
                                               const u16* __restrict__ Bm,
                                               const float* __restrict__ bias,
                                               void* __restrict__ Cout,
                                               int M, int N, int K) {
  __shared__ u16 As[2][BM * 32];
  __shared__ u16 Bs[2][BN * 32];
  constexpr int MT = BM / 32, NT = BN / 32;   // per-wave 16x16 tiles (2x2 wave grid)
  const int nb = N / BN;
  const int m0 = (int)(blockIdx.x / nb) * BM;
  const int n0 = (int)(blockIdx.x % nb) * BN;
  const int tid = threadIdx.x;
  const int w = tid >> 6, lane = tid & 63;
  const int wm = (w >> 1) * (BM / 2), wn = (w & 1) * (BN / 2);
  const int lr = lane & 15, lg = lane >> 4;

  f32x4 acc[MT][NT];
  const f32x4 z4 = {0.f, 0.f, 0.f, 0.f};
#pragma unroll
  for (int m = 0; m < MT; ++m)
#pragma unroll
    for (int n = 0; n < NT; ++n) acc[m][n] = z4;

  auto stage = [&](int ks, int buf) {
    const int k0 = ks << 5;
#pragma unroll
    for (int i = 0; i < BM * 4 / 256; ++i) {
      const int o = i * 256 + tid;
      const int row = o >> 2, c = o & 3;
      gload_lds16(A + (size_t)(m0 + row) * K + k0 + c * 8, &As[buf][(i * 256 + w * 64) * 8]);
    }
#pragma unroll
    for (int i = 0; i < BN * 4 / 256; ++i) {
      const int o = i * 256 + tid;
      const int row = o >> 2, c = o & 3;
      gload_lds16(Bm + (size_t)(n0 + row) * K + k0 + c * 8, &Bs[buf][(i * 256 + w * 64) * 8]);
    }
  };

  const int nk = K >> 5;
  stage(0, 0);
  __syncthreads();
  for (int ks = 0; ks < nk; ++ks) {
    const int cur = ks & 1;
    if (ks + 1 < nk) stage(ks + 1, cur ^ 1);
    bf16x8 af[MT], bfr[NT];
#pragma unroll
    for (int m = 0; m < MT; ++m)
      af[m] = *(const bf16x8*)&As[cur][(wm + m * 16 + lr) * 32 + lg * 8];
#pragma unroll
    for (int n = 0; n < NT; ++n)
      bfr[n] = *(const bf16x8*)&Bs[cur][(wn + n * 16 + lr) * 32 + lg * 8];
    __builtin_amdgcn_s_setprio(1);
#pragma unroll
    for (int m = 0; m < MT; ++m)
#pragma unroll
      for (int n = 0; n < NT; ++n)
        acc[m][n] = __builtin_amdgcn_mfma_f32_16x16x32_bf16(af[m], bfr[n], acc[m][n], 0, 0, 0);
    __builtin_amdgcn_s_setprio(0);
    __syncthreads();
  }

#pragma unroll
  for (int n = 0; n < NT; ++n) {
    const int e = n0 + wn + n * 16 + lr;
    const float bv = bias[e];
#pragma unroll
    for (int m = 0; m < MT; ++m) {
#pragma unroll
      for (int r = 0; r < 4; ++r) {
        const int row = m0 + wm + m * 16 + lg * 4 + r;   // D: col=lane&15, row=(lane>>4)*4+r
        const float v = acc[m][n][r] + bv;
        if (EPI == 0) {
          ((float*)Cout)[(size_t)row * N + e] = v;
        } else {
          const int which = e >> 10, h = (e >> 6) & 15, d = e & 63;
          const int b = row >> 11, s = row & 2047;
          ((u16*)Cout)[(size_t)which * 4194304 + (((size_t)(b * 16 + h) * 2048 + s) << 6) + d] =
              f2bf(v);
        }
      }
    }
  }
}

// ---------------- V transpose: [bh][t][d] -> [bh][d][t] ----------------
__global__ __launch_bounds__(256) void vtrans(const u16* __restrict__ V, u16* __restrict__ Vt) {
  __shared__ u16 tile[64][72];
  const int bh = blockIdx.x >> 5, t0 = (int)(blockIdx.x & 31) << 6;
  const int tid = threadIdx.x;
  {
    const int tr = tid >> 2, dc = (tid & 3) << 4;
    const u16* src = V + ((size_t)bh * 2048 + t0 + tr) * 64 + dc;
    *(int4*)&tile[tr][dc] = *(const int4*)src;
    *(int4*)&tile[tr][dc + 8] = *(const int4*)(src + 8);
  }
  __syncthreads();
  {
    const int dr = tid >> 2, ts = (tid & 3) << 4;
    unsigned pk[8];
#pragma unroll
    for (int j = 0; j < 8; ++j)
      pk[j] = (unsigned)tile[ts + 2 * j][dr] | ((unsigned)tile[ts + 2 * j + 1][dr] << 16);
    u16* dst = Vt + ((size_t)bh * 64 + dr) * 2048 + t0 + ts;
    *(int4*)dst = *(int4*)&pk[0];
    *(int4*)(dst + 8) = *(int4*)&pk[4];
  }
}

// ---------------- fused attention (swapped QK^T: per-lane q-row softmax) ----------------
// grid: 1024 blocks (XCD-chunk-swizzled) = bh(32) x qtile(32). 4 waves x 16 q-rows.
// D of mfma(K,Q): col(lane&15)=q, row((lane>>4)*4+r)=t  ->  lane owns ONE q-row.
// pass 1: per-lane online (m,l), merge via 2 shfl_xor at end (no per-tile shuffles).
// pass 2: recompute scores, float4 weight stores, P->bf16 via cvt_pk through
//         per-wave XOR-swizzled LDS into PV A-fragments.
__global__ __launch_bounds__(256) void attn(const u16* __restrict__ Q,
                                            const u16* __restrict__ Kg,
                                            const u16* __restrict__ Vtg,
                                            const int* __restrict__ mask,
                                            float* __restrict__ Wout,
                                            u16* __restrict__ Og) {
  __shared__ u16 Ks[2][64 * 64];
  __shared__ u16 Vs[2][64 * 64];
  __shared__ u16 Pl[4][16 * 64];   // per-wave [16 q][64 t] bf16, XOR-swizzled
  const int L = ((int)blockIdx.x & 7) * 128 + ((int)blockIdx.x >> 3);  // XCD chunking
  const int bh = L >> 5, qt = L & 31;
  const int b = bh >> 4, h = bh & 15;
  const int tid = threadIdx.x;
  const int w = tid >> 6, lane = tid & 63;
  const int lr = lane & 15, lg = lane >> 4;
  const int srow0 = qt * 64 + w * 16;

  const u16* qrow = Q + ((size_t)bh * 2048 + srow0 + lr) * 64;
  const bf16x8 qf0 = *(const bf16x8*)(qrow + lg * 8);
  const bf16x8 qf1 = *(const bf16x8*)(qrow + 32 + lg * 8);
  const int* mrow = mask + b * 2048;

  auto stageK = [&](int kt, int buf) {
    const u16* g = Kg + ((size_t)bh * 2048 + kt * 64) * 64;
#pragma unroll
    for (int iss = 0; iss < 2; ++iss) {
      const int o = iss * 256 + tid;
      const int row = o >> 3, c = o & 7;   // pre-swizzled global source, linear LDS dest
      gload_lds16(g + row * 64 + ((c ^ (row & 7)) << 3), &Ks[buf][(iss * 256 + w * 64) * 8]);
    }
  };
  auto stageV = [&](int kt, int buf) {
    const u16* g = Vtg + (size_t)bh * 131072 + kt * 64;
#pragma unroll
    for (int iss = 0; iss < 2; ++iss) {
      const int o = iss * 256 + tid;
      const int row = o >> 3, c = o & 7;
      gload_lds16(g + (size_t)row * 2048 + ((c ^ (row & 7)) << 3),
                  &Vs[buf][(iss * 256 + w * 64) * 8]);
    }
  };
  // sc[n][r] = score[q = srow0+lr][t = kt*64 + n*16 + lg*4 + r] (masked)
  auto scores = [&](int cur, int kt, f32x4* sc) {
    const f32x4 z4 = {0.f, 0.f, 0.f, 0.f};
    __builtin_amdgcn_s_setprio(1);
#pragma unroll
    for (int n = 0; n < 4; ++n) {
      const int tr = n * 16 + lr;
      const bf16x8 k0 = *(const bf16x8*)&Ks[cur][tr * 64 + ((lg ^ (tr & 7)) << 3)];
      const bf16x8 k1 = *(const bf16x8*)&Ks[cur][tr * 64 + (((lg + 4) ^ (tr & 7)) << 3)];
      f32x4 s = z4;
      s = __builtin_amdgcn_mfma_f32_16x16x32_bf16(k0, qf0, s, 0, 0, 0);
      s = __builtin_amdgcn_mfma_f32_16x16x32_bf16(k1, qf1, s, 0, 0, 0);
      const int4 mv = *(const int4*)&mrow[kt * 64 + n * 16 + lg * 4];
      if (mv.x == 0) s[0] = -4e30f;
      if (mv.y == 0) s[1] = -4e30f;
      if (mv.z == 0) s[2] = -4e30f;
      if (mv.w == 0) s[3] = -4e30f;
      sc[n] = s;
    }
    __builtin_amdgcn_s_setprio(0);
  };

  float mreg = -1e30f, lreg = 0.f;

  // ---- pass 1: per-lane online row stats ----
  stageK(0, 0);
  __syncthreads();
  for (int kt = 0; kt < 32; ++kt) {
    const int cur = kt & 1;
    if (kt + 1 < 32) stageK(kt + 1, cur ^ 1);
    f32x4 sc[4];
    scores(cur, kt, sc);
    float tm = -1e30f;
#pragma unroll
    for (int n = 0; n < 4; ++n)
      tm = fmaxf(tm, fmaxf(fmaxf(sc[n][0], sc[n][1]), fmaxf(sc[n][2], sc[n][3])));
    const float mn = fmaxf(mreg, tm);
    float s = 0.f;
#pragma unroll
    for (int n = 0; n < 4; ++n)
#pragma unroll
      for (int r = 0; r < 4; ++r) s += __expf(0.125f * (sc[n][r] - mn));
    lreg = lreg * __expf(0.125f * (mreg - mn)) + s;
    mreg = mn;
    __syncthreads();
  }
  // merge the 4 lanes (lg group) sharing this q-row
#pragma unroll
  for (int msk = 16; msk <= 32; msk <<= 1) {
    const float mo = __shfl_xor(mreg, msk);
    const float lo = __shfl_xor(lreg, msk);
    const float mn = fmaxf(mreg, mo);
    lreg = lreg * __expf(0.125f * (mreg - mn)) + lo * __expf(0.125f * (mo - mn));
    mreg = mn;
  }
  const float rl = 1.0f / lreg;

  // ---- pass 2: weights + PV ----
  stageK(0, 0);
  stageV(0, 0);
  __syncthreads();

  f32x4 oacc[4];
  const f32x4 z4 = {0.f, 0.f, 0.f, 0.f};
#pragma unroll
  for (int n = 0; n < 4; ++n) oacc[n] = z4;

  float* wrow = Wout + ((size_t)bh * 2048 + srow0 + lr) * 2048;   // per-lane q-row
  char* plw = (char*)&Pl[w][0];
  const int pswz = (lr & 3) << 5;   // XOR on byte-offset bits 5-6

  for (int kt = 0; kt < 32; ++kt) {
    const int cur = kt & 1;
    if (kt + 1 < 32) { stageK(kt + 1, cur ^ 1); stageV(kt + 1, cur ^ 1); }
    f32x4 sc[4];
    scores(cur, kt, sc);
#pragma unroll
    for (int n = 0; n < 4; ++n) {
      f32x4 wv;
#pragma unroll
      for (int r = 0; r < 4; ++r) wv[r] = __expf(0.125f * (sc[n][r] - mreg)) * rl;
      *(f32x4*)&wrow[kt * 64 + n * 16 + lg * 4] = wv;      // float4 weight store
      uint2 pw;
      pw.x = cvtpk(wv[0], wv[1]);
      pw.y = cvtpk(wv[2], wv[3]);
      *(uint2*)(plw + (lr * 128 + ((n * 32 + lg * 8) ^ pswz))) = pw;
    }
    // PV A-fragments: lane needs P[q=lr][t = c*32 + lg*8 .. +7]
    const bf16x8 pf0 = *(const bf16x8*)(plw + (lr * 128 + ((lg * 16) ^ pswz)));
    const bf16x8 pf1 = *(const bf16x8*)(plw + (lr * 128 + ((64 + lg * 16) ^ pswz)));
    __builtin_amdgcn_s_setprio(1);
#pragma unroll
    for (int n = 0; n < 4; ++n) {
      const int dr = n * 16 + lr;
      const bf16x8 v0 = *(const bf16x8*)&Vs[cur][dr * 64 + ((lg ^ (dr & 7)) << 3)];
      const bf16x8 v1 = *(const bf16x8*)&Vs[cur][dr * 64 + (((lg + 4) ^ (dr & 7)) << 3)];
      oacc[n] = __builtin_amdgcn_mfma_f32_16x16x32_bf16(pf0, v0, oacc[n], 0, 0, 0);
      oacc[n] = __builtin_amdgcn_mfma_f32_16x16x32_bf16(pf1, v1, oacc[n], 0, 0, 0);
    }
    __builtin_amdgcn_s_setprio(0);
    __syncthreads();
  }

  // O: lane holds O[q = srow0 + lg*4 + r][d = n*16 + lr]
#pragma unroll
  for (int n = 0; n < 4; ++n) {
#pragma unroll
    for (int r = 0; r < 4; ++r) {
      const int s = srow0 + lg * 4 + r;
      Og[((size_t)(b * 2048 + s)) * 1024 + h * 64 + n * 16 + lr] = f2bf(oacc[n][r]);
    }
  }
}

// ---------------- launch ----------------
extern "C" void kernel_launch(void* const* d_in, const int* in_sizes, int n_in,
                              void* d_out, int out_size, void* d_ws, size_t ws_size,
                              hipStream_t stream) {
  const float* x     = (const float*)d_in[0];
  const int*   mask  = (const int*)d_in[1];
  const float* qkv_w = (const float*)d_in[2];
  const float* qkv_b = (const float*)d_in[3];
  const float* wo_w  = (const float*)d_in[4];
  const float* wo_b  = (const float*)d_in[5];
  float* out = (float*)d_out;

  char* ws = (char*)d_ws;
  u16* xb   = (u16*)(ws);                          // 4096x1024
  u16* qwb  = (u16*)(ws + (8u << 20));             // 3072x1024
  u16* wob  = (u16*)(ws + (14u << 20));            // 1024x1024
  u16* qkvb = (u16*)(ws + (16u << 20));            // 3 x [bh][s][64] bf16
  u16* vt   = (u16*)(ws + (40u << 20));            // [bh][64][2048] bf16
  u16* ob   = (u16*)(ws + (48u << 20));            // attn out [4096][1024] bf16

  cvt_bf16<<<4096, 256, 0, stream>>>(x, xb, 4194304);
  cvt_bf16<<<3072, 256, 0, stream>>>(qkv_w, qwb, 3145728);
  cvt_bf16<<<1024, 256, 0, stream>>>(wo_w, wob, 1048576);
  gemm_bt<1, 128, 128><<<768, 256, 0, stream>>>(xb, qwb, qkv_b, qkvb, 4096, 3072, 1024);
  vtrans<<<1024, 256, 0, stream>>>(qkvb + 2 * 4194304, vt);
  attn<<<1024, 256, 0, stream>>>(qkvb, qkvb + 4194304, vt, mask, out + 4194304, ob);
  gemm_bt<0, 64, 64><<<1024, 256, 0, stream>>>(ob, wob, wo_b, out, 4096, 1024, 1024);
}